// Round 1
// baseline (6072.136 us; speedup 1.0000x reference)
//
#include <hip/hip_runtime.h>
#include <hip/hip_bf16.h>

typedef __hip_bfloat16 bf16;
typedef __attribute__((ext_vector_type(8))) short v8bf;     // 8 bf16 (4 VGPR)
typedef __attribute__((ext_vector_type(16))) float f32x16;
typedef __attribute__((ext_vector_type(4))) unsigned short us4;

#define B_    256
#define SEED_ 120
#define PRED_ 24
#define D_    126
#define H_    1024
#define F_    61
#define HEADS_ 4
#define DH_   256

__device__ inline unsigned short f2b(float f){ bf16 h = __float2bfloat16(f); return *(unsigned short*)&h; }
__device__ inline float b2f(unsigned short u){ return __uint_as_float(((unsigned)u) << 16); }

// ---------------- small precompute kernels ----------------
__global__ void k_cos(float* cosT){
  int i = blockIdx.x*256 + threadIdx.x;
  if (i < F_*SEED_){
    int f = i / SEED_, t = i % SEED_;
    int ph = (f*t) % SEED_;
    cosT[i] = cosf(6.283185307179586f * (float)ph / (float)SEED_);
  }
}

__global__ void k_dft(const float* __restrict__ poses, const float* __restrict__ cosT,
                      float* __restrict__ freq){
  int f = blockIdx.x, b = blockIdx.y, d = threadIdx.x;  // block 128
  if (d >= D_) return;
  const float* pb = poses + (size_t)b*(SEED_+PRED_)*D_ + d;
  const float* ct = cosT + f*SEED_;
  float acc = 0.f;
  for (int t = 0; t < SEED_; ++t) acc += ct[t] * pb[(size_t)t*D_];
  freq[((size_t)b*F_ + f)*D_ + d] = acc;
}

__global__ void c_poses(const float* __restrict__ poses, bf16* __restrict__ pb){
  int t = blockIdx.x, b = blockIdx.y, c = threadIdx.x;  // block 128
  float v = (c < D_) ? poses[((size_t)b*(SEED_+PRED_) + t)*D_ + c] : 0.f;
  pb[((size_t)t*B_ + b)*128 + c] = __float2bfloat16(v);
}

__global__ void c_xinit(const float* __restrict__ poses, float* __restrict__ x, bf16* __restrict__ xbf){
  int b = blockIdx.x, c = threadIdx.x;  // block 128
  float v = (c < D_) ? poses[((size_t)b*(SEED_+PRED_) + (SEED_-1))*D_ + c] : 0.f;
  if (c < D_) x[b*D_ + c] = v;
  xbf[b*128 + c] = __float2bfloat16(v);
}

__global__ void c_bf(const float* __restrict__ s, bf16* __restrict__ d, int n){
  int i = blockIdx.x*256 + threadIdx.x;
  if (i < n) d[i] = __float2bfloat16(s[i]);
}

__global__ void c_fpwt(const float* __restrict__ fpW, bf16* __restrict__ o){
  int dd = blockIdx.x;                       // 0..127
  for (int k = threadIdx.x; k < H_; k += 256)
    o[(size_t)dd*H_ + k] = __float2bfloat16(dd < D_ ? fpW[(size_t)k*D_ + dd] : 0.f);
}

__global__ void c_w1hid(const float* __restrict__ W1, bf16* __restrict__ o){
  int i = blockIdx.x*256 + threadIdx.x;      // 1792*1024
  if (i < 1792*1024){ int r = i >> 10, c = i & 1023; o[i] = __float2bfloat16(W1[(size_t)r*1033 + c]); }
}

// combined GRU weight: rows 0..2047 = [Wih|Whh] (r,z); 2048..3071 = [Wih_n|0]; 3072..4095 = [0|Whh_n]
__global__ void c_wcat(const float* __restrict__ Wih, const float* __restrict__ Whh, bf16* __restrict__ o){
  int r = blockIdx.x;
  int jr; bool hasx, hash;
  if (r < 2048){ jr = r; hasx = true; hash = true; }
  else if (r < 3072){ jr = r; hasx = true; hash = false; }
  else { jr = r - 1024; hasx = false; hash = true; }
  bf16* row = o + (size_t)r*1152;
  for (int c = threadIdx.x; c < 1152; c += 256){
    float v = 0.f;
    if (c < D_) { if (hasx) v = Wih[(size_t)jr*D_ + c]; }
    else if (c >= 128){ if (hash) v = Whh[(size_t)jr*H_ + (c-128)]; }
    row[c] = __float2bfloat16(v);
  }
}

__global__ void c_bcat(const float* __restrict__ bih, const float* __restrict__ bhh, float* __restrict__ o){
  int r = blockIdx.x*256 + threadIdx.x;
  if (r >= 4096) return;
  float v;
  if (r < 2048) v = bih[r] + bhh[r];
  else if (r < 3072) v = bih[r];
  else v = bhh[r - 1024];
  o[r] = v;
}

__global__ void k_bc(const float* __restrict__ inW, const float* __restrict__ inb,
                     const float* __restrict__ fpb, float* __restrict__ bc){
  int n = blockIdx.x*64 + threadIdx.x;   // grid 48 x 64
  float acc = inb[n];
  for (int k = 0; k < H_; ++k) acc += inW[(size_t)n*H_ + k] * fpb[k];
  bc[n] = acc;
}

// ---------------- generic MFMA GEMM: C[M,N] = [A1|A2] @ B^T (+bias, epilogue) ----------------
// A1: M x K1, A2: M x K2 (bf16, row-major); B: N x (K1+K2) bf16 row-major.
// grid (M/64, N/64), block 256 (4 waves, each a 32x32 quadrant via mfma_f32_32x32x16_bf16)
__global__ __launch_bounds__(256) void mfma_gemm(
    const bf16* __restrict__ A1, int K1, const bf16* __restrict__ A2, int K2,
    const bf16* __restrict__ Bm, const float* __restrict__ bias,
    const float* __restrict__ addmat, float* __restrict__ C, bf16* __restrict__ Cbf,
    int N, int MODE)
{
  __shared__ bf16 As[64*16];
  __shared__ bf16 Bs[64*16];
  int m0 = blockIdx.x*64, n0 = blockIdx.y*64;
  int tid = threadIdx.x;
  int wave = tid >> 6, lane = tid & 63;
  int wm = (wave >> 1)*32, wn = (wave & 1)*32;
  int srow = tid >> 2, skq = (tid & 3)*4;
  int Ktot = K1 + K2, KT = Ktot >> 4;
  int fr = lane & 31, kh = (lane >> 5)*8;
  f32x16 acc = {0.f,0.f,0.f,0.f,0.f,0.f,0.f,0.f,0.f,0.f,0.f,0.f,0.f,0.f,0.f,0.f};

  uint2 ra, rb;
  {
    int kb = skq;
    const bf16* pa = (kb < K1) ? (A1 + (size_t)(m0+srow)*K1 + kb)
                               : (A2 + (size_t)(m0+srow)*K2 + (kb - K1));
    const bf16* pbp = Bm + (size_t)(n0+srow)*Ktot + kb;
    ra = *(const uint2*)pa; rb = *(const uint2*)pbp;
  }
  for (int kt = 0; kt < KT; ++kt){
    __syncthreads();
    *(uint2*)&As[srow*16 + skq] = ra;
    *(uint2*)&Bs[srow*16 + skq] = rb;
    __syncthreads();
    if (kt + 1 < KT){
      int kb = (kt+1)*16 + skq;
      const bf16* pa = (kb < K1) ? (A1 + (size_t)(m0+srow)*K1 + kb)
                                 : (A2 + (size_t)(m0+srow)*K2 + (kb - K1));
      const bf16* pbp = Bm + (size_t)(n0+srow)*Ktot + kb;
      ra = *(const uint2*)pa; rb = *(const uint2*)pbp;
    }
    v8bf av = *(const v8bf*)&As[(wm+fr)*16 + kh];
    v8bf bv = *(const v8bf*)&Bs[(wn+fr)*16 + kh];
    acc = __builtin_amdgcn_mfma_f32_32x32x16_bf16(av, bv, acc, 0, 0, 0);
  }
  #pragma unroll
  for (int r = 0; r < 16; ++r){
    int row = m0 + wm + (r&3) + 8*(r>>2) + 4*(lane>>5);
    int col = n0 + wn + fr;
    float v = acc[r];
    if (bias) v += bias[col];
    if (MODE == 1) v = fmaxf(v, 0.f) + addmat[(size_t)row*N + col];
    C[(size_t)row*N + col] = v;
    if (Cbf) Cbf[(size_t)row*N + col] = __float2bfloat16(v);
  }
}

// ---------------- attention ----------------
// per (head,b): q,k (61 x 256) via W_c (fused inproj@fp_W), scores -> att (global)
__global__ __launch_bounds__(256) void k_qk(const float* __restrict__ Wc, const float* __restrict__ bc,
                     const float* __restrict__ freq, float* __restrict__ att){
  __shared__ unsigned short qs[F_*260];
  __shared__ unsigned short ks[F_*260];
  int h = blockIdx.x, b = blockIdx.y, tid = threadIdx.x;
  int nQ = h*DH_ + tid, nK = H_ + h*DH_ + tid;
  const float* fb = freq + (size_t)b*F_*D_;
  for (int c = 0; c < 2; ++c){
    float wq[63], wk[63];
    const float* wqp = Wc + (size_t)nQ*128 + c*63;
    const float* wkp = Wc + (size_t)nK*128 + c*63;
    #pragma unroll
    for (int i = 0; i < 63; ++i){ wq[i] = wqp[i]; wk[i] = wkp[i]; }
    #pragma unroll 1
    for (int f = 0; f < F_; ++f){
      const float* frp = fb + f*D_ + c*63;
      float sq = 0.f, sk = 0.f;
      #pragma unroll
      for (int i = 0; i < 63; ++i){ float fv = frp[i]; sq += wq[i]*fv; sk += wk[i]*fv; }
      if (c == 0){ qs[f*260+tid] = f2b(sq + bc[nQ]); ks[f*260+tid] = f2b(sk + bc[nK]); }
      else {
        qs[f*260+tid] = f2b(b2f(qs[f*260+tid]) + sq);
        ks[f*260+tid] = f2b(b2f(ks[f*260+tid]) + sk);
      }
    }
  }
  __syncthreads();
  int tq = tid >> 4, tk = tid & 15;
  float s[4][4] = {{0.f}};
  for (int d0 = 0; d0 < DH_; d0 += 4){
    float qv[4][4], kv[4][4];
    #pragma unroll
    for (int i = 0; i < 4; ++i){
      int qq = tq*4 + i; if (qq > F_-1) qq = F_-1;
      int kk = tk*4 + i; if (kk > F_-1) kk = F_-1;
      us4 q4 = *(const us4*)&qs[qq*260 + d0];
      us4 k4 = *(const us4*)&ks[kk*260 + d0];
      #pragma unroll
      for (int jj = 0; jj < 4; ++jj){ qv[i][jj] = b2f(q4[jj]); kv[i][jj] = b2f(k4[jj]); }
    }
    #pragma unroll
    for (int i = 0; i < 4; ++i)
      #pragma unroll
      for (int jj = 0; jj < 4; ++jj)
        #pragma unroll
        for (int dd = 0; dd < 4; ++dd)
          s[i][jj] += qv[i][dd] * kv[jj][dd];
  }
  float* ab = att + (size_t)(b*HEADS_ + h)*F_*F_;
  const float inv = 0.0625f;  // 1/sqrt(256)
  #pragma unroll
  for (int i = 0; i < 4; ++i){
    int qq = tq*4 + i; if (qq >= F_) continue;
    #pragma unroll
    for (int jj = 0; jj < 4; ++jj){
      int kk = tk*4 + jj; if (kk >= F_) continue;
      ab[qq*F_ + kk] = s[i][jj]*inv;
    }
  }
}

__global__ void k_soft(float* __restrict__ att, float* __restrict__ colsum){
  int h = blockIdx.x, b = blockIdx.y, t = threadIdx.x;  // block 64
  float* ab = att + (size_t)(b*HEADS_ + h)*F_*F_;
  if (t < F_){
    float m = -1e30f;
    for (int k = 0; k < F_; ++k) m = fmaxf(m, ab[t*F_+k]);
    float sum = 0.f;
    for (int k = 0; k < F_; ++k){ float e = __expf(ab[t*F_+k] - m); ab[t*F_+k] = e; sum += e; }
    float is = 1.f/sum;
    for (int k = 0; k < F_; ++k) ab[t*F_+k] *= is;
  }
  __syncthreads();
  if (t < F_){
    float cs = 0.f;
    for (int r = 0; r < F_; ++r) cs += ab[r*F_ + t];
    colsum[(size_t)(b*HEADS_ + h)*F_ + t] = cs;
  }
}

__global__ __launch_bounds__(256) void k_vctx(const float* __restrict__ Wc, const float* __restrict__ bc,
                      const float* __restrict__ freq, const float* __restrict__ colsum,
                      bf16* __restrict__ ctxbf){
  __shared__ unsigned short vs[F_*260];
  int h = blockIdx.x, b = blockIdx.y, tid = threadIdx.x;
  int nV = 2*H_ + h*DH_ + tid;
  const float* fb = freq + (size_t)b*F_*D_;
  for (int c = 0; c < 2; ++c){
    float wv[63];
    const float* wvp = Wc + (size_t)nV*128 + c*63;
    #pragma unroll
    for (int i = 0; i < 63; ++i) wv[i] = wvp[i];
    #pragma unroll 1
    for (int f = 0; f < F_; ++f){
      const float* frp = fb + f*D_ + c*63;
      float sv = 0.f;
      #pragma unroll
      for (int i = 0; i < 63; ++i) sv += wv[i]*frp[i];
      if (c == 0) vs[f*260+tid] = f2b(sv + bc[nV]);
      else        vs[f*260+tid] = f2b(b2f(vs[f*260+tid]) + sv);
    }
  }
  __syncthreads();
  const float* cs = colsum + (size_t)(b*HEADS_ + h)*F_;
  float acc = 0.f;
  for (int k = 0; k < F_; ++k) acc += cs[k] * b2f(vs[k*260+tid]);
  ctxbf[(size_t)b*H_ + h*DH_ + tid] = __float2bfloat16(acc * (1.f/61.f));
}

// ---------------- GRU gate ----------------
__global__ void k_gate(const float* __restrict__ G, float* __restrict__ h, bf16* __restrict__ hbf){
  int i = blockIdx.x*256 + threadIdx.x;   // grid 1024
  int b = i >> 10, j = i & 1023;
  const float* g = G + (size_t)b*4096;
  float r = 1.f/(1.f + __expf(-g[j]));
  float z = 1.f/(1.f + __expf(-g[1024+j]));
  float n = tanhf(g[2048+j] + r*g[3072+j]);
  float hv = (1.f - z)*n + z*h[i];
  h[i] = hv; hbf[i] = __float2bfloat16(hv);
}

// ---------------- SPL: parent chains + W2 head (hid-part comes from GEMM) ----------------
__constant__ int LVJ[14] = {0,1,6,8,9, 2,3,7,10,11, 4,5,12,13};
__constant__ int LVO[4]  = {0,5,10,14};
__constant__ int PAR_[14] = {-1,-1,0,1,2,3,-1,6,-1,-1,8,9,10,11};

__global__ __launch_bounds__(128) void spl_all(const float* __restrict__ hh_pre, const float* __restrict__ W1,
                        const float* __restrict__ W2, const float* __restrict__ b2,
                        float* __restrict__ preds_g){
  __shared__ float preds_s[4][128];
  __shared__ float hh_s[128][5];
  int b0 = blockIdx.x*4, t = threadIdx.x;   // grid 64, block 128
  for (int L = 0; L < 3; ++L){
    for (int ji = LVO[L]; ji < LVO[L+1]; ++ji){
      int j = LVJ[ji], p = PAR_[j];
      float acc[4];
      #pragma unroll
      for (int bb = 0; bb < 4; ++bb) acc[bb] = hh_pre[(size_t)(b0+bb)*1792 + j*128 + t];
      if (p >= 0){
        #pragma unroll
        for (int ii = 0; ii < 9; ++ii){
          float w = W1[(size_t)(j*128 + t)*1033 + 1024 + ii];
          #pragma unroll
          for (int bb = 0; bb < 4; ++bb) acc[bb] += w * preds_s[bb][p*9 + ii];
        }
      }
      #pragma unroll
      for (int bb = 0; bb < 4; ++bb) hh_s[t][bb] = fmaxf(acc[bb], 0.f);
      __syncthreads();
      if (t < 36){
        int bb = t/9, oi = t%9;
        float s = b2[j*9 + oi];
        for (int tt = 0; tt < 128; ++tt) s += hh_s[tt][bb] * W2[(size_t)(j*9 + oi)*128 + tt];
        preds_s[bb][j*9 + oi] = tanhf(s);
      }
      __syncthreads();
    }
  }
  for (int i = t; i < 4*D_; i += 128){
    int bb = i / D_, d = i % D_;
    preds_g[(size_t)(b0+bb)*D_ + d] = preds_s[bb][d];
  }
}

__global__ void k_xout(const float* __restrict__ preds_g, float* __restrict__ x, bf16* __restrict__ xbf,
                       float* __restrict__ out, int t){
  int i = blockIdx.x*256 + threadIdx.x;   // grid 126
  if (i >= B_*D_) return;
  int b = i / D_, d = i % D_;
  float v = x[i] + preds_g[i];
  x[i] = v;
  xbf[b*128 + d] = __float2bfloat16(v);
  out[((size_t)b*PRED_ + t)*D_ + d] = v;
}

// ---------------- launch ----------------
extern "C" void kernel_launch(void* const* d_in, const int* in_sizes, int n_in,
                              void* d_out, int out_size, void* d_ws, size_t ws_size,
                              hipStream_t stream){
  (void)in_sizes; (void)n_in; (void)out_size; (void)ws_size;
  const float* poses = (const float*)d_in[0];
  const float* gWih  = (const float*)d_in[1];
  const float* gWhh  = (const float*)d_in[2];
  const float* gbih  = (const float*)d_in[3];
  const float* gbhh  = (const float*)d_in[4];
  const float* preW  = (const float*)d_in[5];
  const float* preb  = (const float*)d_in[6];
  const float* fpW   = (const float*)d_in[7];
  const float* fpb   = (const float*)d_in[8];
  const float* inW   = (const float*)d_in[9];
  const float* inb   = (const float*)d_in[10];
  const float* outW  = (const float*)d_in[11];
  const float* outb  = (const float*)d_in[12];
  const float* sW1   = (const float*)d_in[13];
  const float* sb1   = (const float*)d_in[14];
  const float* sW2   = (const float*)d_in[15];
  const float* sb2   = (const float*)d_in[16];
  float* out = (float*)d_out;

  char* w = (char*)d_ws;
  size_t off = 0;
  auto alloc = [&](size_t bytes)->char*{ char* p = w + off; off += (bytes + 255) & ~(size_t)255; return p; };
  float* cosT   = (float*)alloc(7320*4);
  float* freq   = (float*)alloc((size_t)B_*F_*D_*4);
  float* Wc     = (float*)alloc((size_t)3072*128*4);
  float* bc     = (float*)alloc(3072*4);
  float* att    = (float*)alloc((size_t)B_*HEADS_*F_*F_*4);
  float* colsum = (float*)alloc((size_t)B_*HEADS_*F_*4);
  float* motion = (float*)alloc((size_t)256*1024*4);
  float* hbuf   = (float*)alloc((size_t)256*1024*4);
  float* G      = (float*)alloc((size_t)256*4096*4);
  float* xcur   = (float*)alloc((size_t)256*126*4);
  float* hid    = (float*)alloc((size_t)256*1024*4);
  float* hhpre  = (float*)alloc((size_t)256*1792*4);
  float* predsg = (float*)alloc((size_t)256*126*4);
  bf16* posesbf = (bf16*)alloc((size_t)120*256*128*2);
  bf16* Wcat    = (bf16*)alloc((size_t)4096*1152*2);
  float* bcat   = (float*)alloc(4096*4);
  bf16* prebf   = (bf16*)alloc((size_t)1024*1024*2);
  bf16* outbf   = (bf16*)alloc((size_t)1024*1024*2);
  bf16* inbf    = (bf16*)alloc((size_t)3072*1024*2);
  bf16* fpwt    = (bf16*)alloc((size_t)128*1024*2);
  bf16* w1h     = (bf16*)alloc((size_t)1792*1024*2);
  bf16* ctxbf   = (bf16*)alloc((size_t)256*1024*2);
  bf16* hbf     = (bf16*)alloc((size_t)256*1024*2);
  bf16* xbf     = (bf16*)alloc((size_t)256*128*2);
  bf16* hidbf   = (bf16*)alloc((size_t)256*1024*2);

  hipMemsetAsync(hbuf, 0, (size_t)256*1024*4, stream);
  hipMemsetAsync(hbf, 0, (size_t)256*1024*2, stream);

  k_cos<<<29, 256, 0, stream>>>(cosT);
  k_dft<<<dim3(F_, B_), 128, 0, stream>>>(poses, cosT, freq);
  c_poses<<<dim3(SEED_, B_), 128, 0, stream>>>(poses, posesbf);
  c_xinit<<<B_, 128, 0, stream>>>(poses, xcur, xbf);
  c_wcat<<<4096, 256, 0, stream>>>(gWih, gWhh, Wcat);
  c_bcat<<<16, 256, 0, stream>>>(gbih, gbhh, bcat);
  c_bf<<<4096, 256, 0, stream>>>(preW, prebf, 1024*1024);
  c_bf<<<4096, 256, 0, stream>>>(outW, outbf, 1024*1024);
  c_bf<<<12288, 256, 0, stream>>>(inW, inbf, 3072*1024);
  c_fpwt<<<128, 256, 0, stream>>>(fpW, fpwt);
  c_w1hid<<<7168, 256, 0, stream>>>(sW1, w1h);
  k_bc<<<48, 64, 0, stream>>>(inW, inb, fpb, bc);

  // W_c = inproj @ fp_W  (3072 x 128, cols>=126 are zero)
  mfma_gemm<<<dim3(48, 2), 256, 0, stream>>>(inbf, 1024, nullptr, 0, fpwt, nullptr, nullptr, Wc, nullptr, 128, 0);
  k_qk<<<dim3(HEADS_, B_), 256, 0, stream>>>(Wc, bc, freq, att);
  k_soft<<<dim3(HEADS_, B_), 64, 0, stream>>>(att, colsum);
  k_vctx<<<dim3(HEADS_, B_), 256, 0, stream>>>(Wc, bc, freq, colsum, ctxbf);
  // motion_ctx = ctx_mean @ outproj^T + outb
  mfma_gemm<<<dim3(4, 16), 256, 0, stream>>>(ctxbf, 1024, nullptr, 0, outbf, outb, nullptr, motion, nullptr, 1024, 0);

  // encoder: 120 GRU steps
  for (int t = 0; t < SEED_; ++t){
    mfma_gemm<<<dim3(4, 64), 256, 0, stream>>>(posesbf + (size_t)t*256*128, 128, hbf, 1024,
                                               Wcat, bcat, nullptr, G, nullptr, 4096, 0);
    k_gate<<<1024, 256, 0, stream>>>(G, hbuf, hbf);
  }
  // decoder: 24 steps
  for (int t = 0; t < PRED_; ++t){
    mfma_gemm<<<dim3(4, 64), 256, 0, stream>>>(xbf, 128, hbf, 1024,
                                               Wcat, bcat, nullptr, G, nullptr, 4096, 0);
    k_gate<<<1024, 256, 0, stream>>>(G, hbuf, hbf);
    // hid = relu(h @ pre^T + preb) + motion  (also bf16 copy)
    mfma_gemm<<<dim3(4, 16), 256, 0, stream>>>(hbf, 1024, nullptr, 0, prebf, preb, motion, hid, hidbf, 1024, 1);
    // hh_pre = hid @ W1_hid^T + b1  (all 14 joints)
    mfma_gemm<<<dim3(4, 28), 256, 0, stream>>>(hidbf, 1024, nullptr, 0, w1h, sb1, nullptr, hhpre, nullptr, 1792, 0);
    spl_all<<<64, 128, 0, stream>>>(hhpre, sW1, sW2, sb2, predsg);
    k_xout<<<126, 256, 0, stream>>>(predsg, xcur, xbf, out, t);
  }
}

// Round 2
// 6056.605 us; speedup vs baseline: 1.0026x; 1.0026x over previous
//
#include <hip/hip_runtime.h>
#include <hip/hip_bf16.h>

typedef __hip_bfloat16 bf16;
typedef __attribute__((ext_vector_type(8))) short v8bf;     // 8 bf16 (4 VGPR)
typedef __attribute__((ext_vector_type(16))) float f32x16;
typedef __attribute__((ext_vector_type(4))) unsigned short us4;

#define B_    256
#define SEED_ 120
#define PRED_ 24
#define D_    126
#define H_    1024
#define F_    61
#define HEADS_ 4
#define DH_   256

#define GLD16(lds, g) __builtin_amdgcn_global_load_lds( \
    (const __attribute__((address_space(1))) unsigned int*)(g), \
    (__attribute__((address_space(3))) unsigned int*)(lds), 16, 0, 0)

__device__ inline unsigned short f2b(float f){ bf16 h = __float2bfloat16(f); return *(unsigned short*)&h; }
__device__ inline float b2f(unsigned short u){ return __uint_as_float(((unsigned)u) << 16); }

// ---------------- small precompute kernels ----------------
__global__ void k_cos(float* cosT){
  int i = blockIdx.x*256 + threadIdx.x;
  if (i < F_*SEED_){
    int f = i / SEED_, t = i % SEED_;
    int ph = (f*t) % SEED_;
    cosT[i] = cosf(6.283185307179586f * (float)ph / (float)SEED_);
  }
}

__global__ void k_dft(const float* __restrict__ poses, const float* __restrict__ cosT,
                      float* __restrict__ freq){
  int f = blockIdx.x, b = blockIdx.y, d = threadIdx.x;  // block 128
  if (d >= D_) return;
  const float* pb = poses + (size_t)b*(SEED_+PRED_)*D_ + d;
  const float* ct = cosT + f*SEED_;
  float acc = 0.f;
  for (int t = 0; t < SEED_; ++t) acc += ct[t] * pb[(size_t)t*D_];
  freq[((size_t)b*F_ + f)*D_ + d] = acc;
}

__global__ void c_poses(const float* __restrict__ poses, bf16* __restrict__ pb){
  int t = blockIdx.x, b = blockIdx.y, c = threadIdx.x;  // block 128
  float v = (c < D_) ? poses[((size_t)b*(SEED_+PRED_) + t)*D_ + c] : 0.f;
  pb[((size_t)t*B_ + b)*128 + c] = __float2bfloat16(v);
}

__global__ void c_xinit(const float* __restrict__ poses, float* __restrict__ x, bf16* __restrict__ xbf){
  int b = blockIdx.x, c = threadIdx.x;  // block 128
  float v = (c < D_) ? poses[((size_t)b*(SEED_+PRED_) + (SEED_-1))*D_ + c] : 0.f;
  if (c < D_) x[b*D_ + c] = v;
  xbf[b*128 + c] = __float2bfloat16(v);
}

__global__ void c_bf(const float* __restrict__ s, bf16* __restrict__ d, int n){
  int i = blockIdx.x*256 + threadIdx.x;
  if (i < n) d[i] = __float2bfloat16(s[i]);
}

__global__ void c_fpwt(const float* __restrict__ fpW, bf16* __restrict__ o){
  int dd = blockIdx.x;                       // 0..127
  for (int k = threadIdx.x; k < H_; k += 256)
    o[(size_t)dd*H_ + k] = __float2bfloat16(dd < D_ ? fpW[(size_t)k*D_ + dd] : 0.f);
}

__global__ void c_w1hid(const float* __restrict__ W1, bf16* __restrict__ o){
  int i = blockIdx.x*256 + threadIdx.x;      // 1792*1024
  if (i < 1792*1024){ int r = i >> 10, c = i & 1023; o[i] = __float2bfloat16(W1[(size_t)r*1033 + c]); }
}

// combined GRU weight: rows 0..1023 = [Wih_r|Whh_r]; 1024..2047 = [Wih_z|Whh_z];
// 2048..3071 = [Wih_n|0]; 3072..4095 = [0|Whh_n]   (each row 1152 wide: 128 x-cols | 1024 h-cols)
__global__ void c_wcat(const float* __restrict__ Wih, const float* __restrict__ Whh, bf16* __restrict__ o){
  int r = blockIdx.x;
  int jr; bool hasx, hash;
  if (r < 2048){ jr = r; hasx = true; hash = true; }
  else if (r < 3072){ jr = r; hasx = true; hash = false; }
  else { jr = r - 1024; hasx = false; hash = true; }
  bf16* row = o + (size_t)r*1152;
  for (int c = threadIdx.x; c < 1152; c += 256){
    float v = 0.f;
    if (c < D_) { if (hasx) v = Wih[(size_t)jr*D_ + c]; }
    else if (c >= 128){ if (hash) v = Whh[(size_t)jr*H_ + (c-128)]; }
    row[c] = __float2bfloat16(v);
  }
}

__global__ void c_bcat(const float* __restrict__ bih, const float* __restrict__ bhh, float* __restrict__ o){
  int r = blockIdx.x*256 + threadIdx.x;
  if (r >= 4096) return;
  float v;
  if (r < 2048) v = bih[r] + bhh[r];
  else if (r < 3072) v = bih[r];
  else v = bhh[r - 1024];
  o[r] = v;
}

__global__ void k_bc(const float* __restrict__ inW, const float* __restrict__ inb,
                     const float* __restrict__ fpb, float* __restrict__ bc){
  int n = blockIdx.x*64 + threadIdx.x;   // grid 48 x 64
  float acc = inb[n];
  for (int k = 0; k < H_; ++k) acc += inW[(size_t)n*H_ + k] * fpb[k];
  bc[n] = acc;
}

// ---------------- fused GRU step ----------------
// grid (4 mb, 16 ub), block 256 (4 waves). Each block: 64 batch rows x 64 units, all 4 gate
// accumulators; epilogue applies the GRU gate and writes h_out (fp32 + bf16). h ping-pongs.
// K layout: cols 0..127 = x (xsrc [256][128]); cols 128..1151 = h (hbf_in [256][1024]).
// Wcat supplies zero-padded weights so staging ignores the split; MFMAs on known-zero
// panels are skipped (gate-i only for kt<2, gate-hn only for kt>=2).
__global__ __launch_bounds__(256) void gru_step(
    const bf16* __restrict__ xsrc, const bf16* __restrict__ hbf_in,
    const float* __restrict__ h_in, const bf16* __restrict__ Wcat,
    const float* __restrict__ bcat, float* __restrict__ h_out, bf16* __restrict__ hbf_out)
{
  __shared__ bf16 As[2][64*64];        // 16 KB
  __shared__ bf16 Bs[2][3*64*64];      // 48 KB
  const int tid = threadIdx.x;
  const int wave = tid >> 6, lane = tid & 63;
  const int m0 = blockIdx.x*64, u0 = blockIdx.y*64;
  const int fr = lane & 31, kh = lane >> 5;
  const int wm = (wave >> 1)*32, wn = (wave & 1)*32;

  f32x16 accR = {0.f,0.f,0.f,0.f,0.f,0.f,0.f,0.f,0.f,0.f,0.f,0.f,0.f,0.f,0.f,0.f};
  f32x16 accZ = accR, accI = accR, accN = accR;

  auto STAGE = [&](int buf, int kt){
    #pragma unroll
    for (int q = 0; q < 2; ++q){           // A tile: 64x64, swizzled source
      int idx = q*256 + tid;
      int row = idx >> 3, cp = idx & 7;
      int csw = cp ^ (row & 7);
      const bf16* src = (kt < 2) ? (xsrc   + (size_t)(m0+row)*128  + kt*64      + csw*8)
                                 : (hbf_in + (size_t)(m0+row)*1024 + (kt-2)*64  + csw*8);
      GLD16(&As[buf][idx*8], src);
    }
    #pragma unroll
    for (int q = 0; q < 6; ++q){           // B: 3 gate panels of 64x64
      int idx = q*256 + tid;
      int slot = idx >> 9, wi = idx & 511;
      int row = wi >> 3, cp = wi & 7;
      int csw = cp ^ (row & 7);
      int gate = (slot < 2) ? slot : (kt < 2 ? 2 : 3);
      const bf16* src = Wcat + (size_t)(gate*1024 + u0 + row)*1152 + kt*64 + csw*8;
      GLD16(&Bs[buf][idx*8], src);
    }
  };

  STAGE(0, 0);
  __syncthreads();
  int buf = 0;
  #pragma unroll 2
  for (int kt = 0; kt < 18; ++kt){
    if (kt + 1 < 18) STAGE(buf^1, kt+1);
    const bool xp = (kt < 2);
    const bf16* Ab = &As[buf][0];
    const bf16* Bb = &Bs[buf][0];
    #pragma unroll
    for (int ks = 0; ks < 4; ++ks){
      int ca = ks*2 + kh;
      v8bf av = *(const v8bf*)&Ab[(wm+fr)*64 + ((ca ^ ((wm+fr)&7))*8)];
      int bo = (wn+fr)*64 + ((ca ^ ((wn+fr)&7))*8);
      v8bf br = *(const v8bf*)&Bb[bo];
      v8bf bz = *(const v8bf*)&Bb[4096 + bo];
      v8bf bx = *(const v8bf*)&Bb[8192 + bo];
      accR = __builtin_amdgcn_mfma_f32_32x32x16_bf16(av, br, accR, 0, 0, 0);
      accZ = __builtin_amdgcn_mfma_f32_32x32x16_bf16(av, bz, accZ, 0, 0, 0);
      if (xp) accI = __builtin_amdgcn_mfma_f32_32x32x16_bf16(av, bx, accI, 0, 0, 0);
      else    accN = __builtin_amdgcn_mfma_f32_32x32x16_bf16(av, bx, accN, 0, 0, 0);
    }
    __syncthreads();
    buf ^= 1;
  }

  const int col = u0 + wn + fr;
  const float bR = bcat[col], bZ = bcat[1024+col], bI = bcat[2048+col], bN = bcat[3072+col];
  #pragma unroll
  for (int r = 0; r < 16; ++r){
    int row = m0 + wm + (r&3) + 8*(r>>2) + 4*kh;
    float rg = 1.f/(1.f + __expf(-(accR[r] + bR)));
    float zg = 1.f/(1.f + __expf(-(accZ[r] + bZ)));
    float ng = tanhf((accI[r] + bI) + rg*(accN[r] + bN));
    float ho = h_in[(size_t)row*1024 + col];
    float hv = (1.f - zg)*ng + zg*ho;
    h_out[(size_t)row*1024 + col] = hv;
    hbf_out[(size_t)row*1024 + col] = __float2bfloat16(hv);
  }
}

// ---------------- pipelined generic GEMM: C[M,N] = A @ B^T (+bias/epilogue) ----------------
// A: MxK bf16 row-major, B: NxK bf16 row-major, K % 64 == 0.
// grid (M/64, N/64), block 256. BK=64, double-buffered global_load_lds, XOR-swizzled LDS.
__global__ __launch_bounds__(256) void gemm64(
    const bf16* __restrict__ Am, const bf16* __restrict__ Bm, int K,
    const float* __restrict__ bias, const float* __restrict__ addmat,
    float* __restrict__ C, bf16* __restrict__ Cbf, int N, int MODE)
{
  __shared__ bf16 As[2][64*64];
  __shared__ bf16 Bs[2][64*64];
  const int tid = threadIdx.x;
  const int wave = tid >> 6, lane = tid & 63;
  const int m0 = blockIdx.x*64, n0 = blockIdx.y*64;
  const int fr = lane & 31, kh = lane >> 5;
  const int wm = (wave >> 1)*32, wn = (wave & 1)*32;
  const int KT = K >> 6;

  f32x16 acc = {0.f,0.f,0.f,0.f,0.f,0.f,0.f,0.f,0.f,0.f,0.f,0.f,0.f,0.f,0.f,0.f};

  auto STAGE = [&](int buf, int kt){
    #pragma unroll
    for (int q = 0; q < 2; ++q){
      int idx = q*256 + tid;
      int row = idx >> 3, cp = idx & 7;
      int csw = cp ^ (row & 7);
      GLD16(&As[buf][idx*8], Am + (size_t)(m0+row)*K + kt*64 + csw*8);
    }
    #pragma unroll
    for (int q = 0; q < 2; ++q){
      int idx = q*256 + tid;
      int row = idx >> 3, cp = idx & 7;
      int csw = cp ^ (row & 7);
      GLD16(&Bs[buf][idx*8], Bm + (size_t)(n0+row)*K + kt*64 + csw*8);
    }
  };

  STAGE(0, 0);
  __syncthreads();
  int buf = 0;
  #pragma unroll 2
  for (int kt = 0; kt < KT; ++kt){
    if (kt + 1 < KT) STAGE(buf^1, kt+1);
    const bf16* Ab = &As[buf][0];
    const bf16* Bb = &Bs[buf][0];
    #pragma unroll
    for (int ks = 0; ks < 4; ++ks){
      int ca = ks*2 + kh;
      v8bf av = *(const v8bf*)&Ab[(wm+fr)*64 + ((ca ^ ((wm+fr)&7))*8)];
      v8bf bv = *(const v8bf*)&Bb[(wn+fr)*64 + ((ca ^ ((wn+fr)&7))*8)];
      acc = __builtin_amdgcn_mfma_f32_32x32x16_bf16(av, bv, acc, 0, 0, 0);
    }
    __syncthreads();
    buf ^= 1;
  }

  const int col = n0 + wn + fr;
  float bb = bias ? bias[col] : 0.f;
  #pragma unroll
  for (int r = 0; r < 16; ++r){
    int row = m0 + wm + (r&3) + 8*(r>>2) + 4*kh;
    float v = acc[r] + bb;
    if (MODE == 1) v = fmaxf(v, 0.f) + addmat[(size_t)row*N + col];
    C[(size_t)row*N + col] = v;
    if (Cbf) Cbf[(size_t)row*N + col] = __float2bfloat16(v);
  }
}

// ---------------- attention ----------------
__global__ __launch_bounds__(256) void k_qk(const float* __restrict__ Wc, const float* __restrict__ bc,
                     const float* __restrict__ freq, float* __restrict__ att){
  __shared__ unsigned short qs[F_*260];
  __shared__ unsigned short ks[F_*260];
  int h = blockIdx.x, b = blockIdx.y, tid = threadIdx.x;
  int nQ = h*DH_ + tid, nK = H_ + h*DH_ + tid;
  const float* fb = freq + (size_t)b*F_*D_;
  for (int c = 0; c < 2; ++c){
    float wq[63], wk[63];
    const float* wqp = Wc + (size_t)nQ*128 + c*63;
    const float* wkp = Wc + (size_t)nK*128 + c*63;
    #pragma unroll
    for (int i = 0; i < 63; ++i){ wq[i] = wqp[i]; wk[i] = wkp[i]; }
    #pragma unroll 1
    for (int f = 0; f < F_; ++f){
      const float* frp = fb + f*D_ + c*63;
      float sq = 0.f, sk = 0.f;
      #pragma unroll
      for (int i = 0; i < 63; ++i){ float fv = frp[i]; sq += wq[i]*fv; sk += wk[i]*fv; }
      if (c == 0){ qs[f*260+tid] = f2b(sq + bc[nQ]); ks[f*260+tid] = f2b(sk + bc[nK]); }
      else {
        qs[f*260+tid] = f2b(b2f(qs[f*260+tid]) + sq);
        ks[f*260+tid] = f2b(b2f(ks[f*260+tid]) + sk);
      }
    }
  }
  __syncthreads();
  int tq = tid >> 4, tk = tid & 15;
  float s[4][4] = {{0.f}};
  for (int d0 = 0; d0 < DH_; d0 += 4){
    float qv[4][4], kv[4][4];
    #pragma unroll
    for (int i = 0; i < 4; ++i){
      int qq = tq*4 + i; if (qq > F_-1) qq = F_-1;
      int kk = tk*4 + i; if (kk > F_-1) kk = F_-1;
      us4 q4 = *(const us4*)&qs[qq*260 + d0];
      us4 k4 = *(const us4*)&ks[kk*260 + d0];
      #pragma unroll
      for (int jj = 0; jj < 4; ++jj){ qv[i][jj] = b2f(q4[jj]); kv[i][jj] = b2f(k4[jj]); }
    }
    #pragma unroll
    for (int i = 0; i < 4; ++i)
      #pragma unroll
      for (int jj = 0; jj < 4; ++jj)
        #pragma unroll
        for (int dd = 0; dd < 4; ++dd)
          s[i][jj] += qv[i][dd] * kv[jj][dd];
  }
  float* ab = att + (size_t)(b*HEADS_ + h)*F_*F_;
  const float inv = 0.0625f;  // 1/sqrt(256)
  #pragma unroll
  for (int i = 0; i < 4; ++i){
    int qq = tq*4 + i; if (qq >= F_) continue;
    #pragma unroll
    for (int jj = 0; jj < 4; ++jj){
      int kk = tk*4 + jj; if (kk >= F_) continue;
      ab[qq*F_ + kk] = s[i][jj]*inv;
    }
  }
}

__global__ void k_soft(float* __restrict__ att, float* __restrict__ colsum){
  int h = blockIdx.x, b = blockIdx.y, t = threadIdx.x;  // block 64
  float* ab = att + (size_t)(b*HEADS_ + h)*F_*F_;
  if (t < F_){
    float m = -1e30f;
    for (int k = 0; k < F_; ++k) m = fmaxf(m, ab[t*F_+k]);
    float sum = 0.f;
    for (int k = 0; k < F_; ++k){ float e = __expf(ab[t*F_+k] - m); ab[t*F_+k] = e; sum += e; }
    float is = 1.f/sum;
    for (int k = 0; k < F_; ++k) ab[t*F_+k] *= is;
  }
  __syncthreads();
  if (t < F_){
    float cs = 0.f;
    for (int r = 0; r < F_; ++r) cs += ab[r*F_ + t];
    colsum[(size_t)(b*HEADS_ + h)*F_ + t] = cs;
  }
}

__global__ __launch_bounds__(256) void k_vctx(const float* __restrict__ Wc, const float* __restrict__ bc,
                      const float* __restrict__ freq, const float* __restrict__ colsum,
                      bf16* __restrict__ ctxbf){
  __shared__ unsigned short vs[F_*260];
  int h = blockIdx.x, b = blockIdx.y, tid = threadIdx.x;
  int nV = 2*H_ + h*DH_ + tid;
  const float* fb = freq + (size_t)b*F_*D_;
  for (int c = 0; c < 2; ++c){
    float wv[63];
    const float* wvp = Wc + (size_t)nV*128 + c*63;
    #pragma unroll
    for (int i = 0; i < 63; ++i) wv[i] = wvp[i];
    #pragma unroll 1
    for (int f = 0; f < F_; ++f){
      const float* frp = fb + f*D_ + c*63;
      float sv = 0.f;
      #pragma unroll
      for (int i = 0; i < 63; ++i) sv += wv[i]*frp[i];
      if (c == 0) vs[f*260+tid] = f2b(sv + bc[nV]);
      else        vs[f*260+tid] = f2b(b2f(vs[f*260+tid]) + sv);
    }
  }
  __syncthreads();
  const float* cs = colsum + (size_t)(b*HEADS_ + h)*F_;
  float acc = 0.f;
  for (int k = 0; k < F_; ++k) acc += cs[k] * b2f(vs[k*260+tid]);
  ctxbf[(size_t)b*H_ + h*DH_ + tid] = __float2bfloat16(acc * (1.f/61.f));
}

// ---------------- SPL: parent chains + W2 head + x update (hid-part from GEMM) ----------------
__constant__ int LVJ[14] = {0,1,6,8,9, 2,3,7,10,11, 4,5,12,13};
__constant__ int LVO[4]  = {0,5,10,14};
__constant__ int PAR_[14] = {-1,-1,0,1,2,3,-1,6,-1,-1,8,9,10,11};

__global__ __launch_bounds__(128) void spl_all(const float* __restrict__ hh_pre, const float* __restrict__ W1,
                        const float* __restrict__ W2, const float* __restrict__ b2,
                        float* __restrict__ x, bf16* __restrict__ xbf,
                        float* __restrict__ out, int tstep){
  __shared__ float preds_s[4][128];
  __shared__ float hh_s[128][5];
  int b0 = blockIdx.x*4, t = threadIdx.x;   // grid 64, block 128
  for (int L = 0; L < 3; ++L){
    for (int ji = LVO[L]; ji < LVO[L+1]; ++ji){
      int j = LVJ[ji], p = PAR_[j];
      float acc[4];
      #pragma unroll
      for (int bb = 0; bb < 4; ++bb) acc[bb] = hh_pre[(size_t)(b0+bb)*1792 + j*128 + t];
      if (p >= 0){
        #pragma unroll
        for (int ii = 0; ii < 9; ++ii){
          float w = W1[(size_t)(j*128 + t)*1033 + 1024 + ii];
          #pragma unroll
          for (int bb = 0; bb < 4; ++bb) acc[bb] += w * preds_s[bb][p*9 + ii];
        }
      }
      #pragma unroll
      for (int bb = 0; bb < 4; ++bb) hh_s[t][bb] = fmaxf(acc[bb], 0.f);
      __syncthreads();
      if (t < 72){
        int pp = t >> 1, half = t & 1;
        int bb = pp/9, oi = pp%9;
        const float* w2r = W2 + (size_t)(j*9 + oi)*128 + half*64;
        float s = 0.f;
        #pragma unroll
        for (int tt = 0; tt < 64; ++tt) s += hh_s[half*64 + tt][bb] * w2r[tt];
        s += __shfl_xor(s, 1);
        if (half == 0) preds_s[bb][j*9 + oi] = tanhf(s + b2[j*9 + oi]);
      }
      __syncthreads();
    }
  }
  for (int i = t; i < 4*D_; i += 128){
    int bb = i / D_, d = i % D_;
    size_t xi = (size_t)(b0+bb)*D_ + d;
    float v = x[xi] + preds_s[bb][d];
    x[xi] = v;
    xbf[(size_t)(b0+bb)*128 + d] = __float2bfloat16(v);
    out[((size_t)(b0+bb)*PRED_ + tstep)*D_ + d] = v;
  }
}

// ---------------- launch ----------------
extern "C" void kernel_launch(void* const* d_in, const int* in_sizes, int n_in,
                              void* d_out, int out_size, void* d_ws, size_t ws_size,
                              hipStream_t stream){
  (void)in_sizes; (void)n_in; (void)out_size; (void)ws_size;
  const float* poses = (const float*)d_in[0];
  const float* gWih  = (const float*)d_in[1];
  const float* gWhh  = (const float*)d_in[2];
  const float* gbih  = (const float*)d_in[3];
  const float* gbhh  = (const float*)d_in[4];
  const float* preW  = (const float*)d_in[5];
  const float* preb  = (const float*)d_in[6];
  const float* fpW   = (const float*)d_in[7];
  const float* fpb   = (const float*)d_in[8];
  const float* inW   = (const float*)d_in[9];
  const float* inb   = (const float*)d_in[10];
  const float* outW  = (const float*)d_in[11];
  const float* outb  = (const float*)d_in[12];
  const float* sW1   = (const float*)d_in[13];
  const float* sb1   = (const float*)d_in[14];
  const float* sW2   = (const float*)d_in[15];
  const float* sb2   = (const float*)d_in[16];
  float* out = (float*)d_out;

  char* w = (char*)d_ws;
  size_t off = 0;
  auto alloc = [&](size_t bytes)->char*{ char* p = w + off; off += (bytes + 255) & ~(size_t)255; return p; };
  float* cosT   = (float*)alloc(7320*4);
  float* freq   = (float*)alloc((size_t)B_*F_*D_*4);
  float* Wc     = (float*)alloc((size_t)3072*128*4);
  float* bc     = (float*)alloc(3072*4);
  float* att    = (float*)alloc((size_t)B_*HEADS_*F_*F_*4);
  float* colsum = (float*)alloc((size_t)B_*HEADS_*F_*4);
  float* motion = (float*)alloc((size_t)256*1024*4);
  float* hA     = (float*)alloc((size_t)256*1024*4);
  float* hB     = (float*)alloc((size_t)256*1024*4);
  float* xcur   = (float*)alloc((size_t)256*126*4);
  float* hid    = (float*)alloc((size_t)256*1024*4);
  float* hhpre  = (float*)alloc((size_t)256*1792*4);
  bf16* posesbf = (bf16*)alloc((size_t)120*256*128*2);
  bf16* Wcat    = (bf16*)alloc((size_t)4096*1152*2);
  float* bcat   = (float*)alloc(4096*4);
  bf16* prebf   = (bf16*)alloc((size_t)1024*1024*2);
  bf16* outbf   = (bf16*)alloc((size_t)1024*1024*2);
  bf16* inbf    = (bf16*)alloc((size_t)3072*1024*2);
  bf16* fpwt    = (bf16*)alloc((size_t)128*1024*2);
  bf16* w1h     = (bf16*)alloc((size_t)1792*1024*2);
  bf16* ctxbf   = (bf16*)alloc((size_t)256*1024*2);
  bf16* hbA    = (bf16*)alloc((size_t)256*1024*2);
  bf16* hbB    = (bf16*)alloc((size_t)256*1024*2);
  bf16* xbf     = (bf16*)alloc((size_t)256*128*2);
  bf16* hidbf   = (bf16*)alloc((size_t)256*1024*2);

  hipMemsetAsync(hA, 0, (size_t)256*1024*4, stream);
  hipMemsetAsync(hbA, 0, (size_t)256*1024*2, stream);

  k_cos<<<29, 256, 0, stream>>>(cosT);
  k_dft<<<dim3(F_, B_), 128, 0, stream>>>(poses, cosT, freq);
  c_poses<<<dim3(SEED_, B_), 128, 0, stream>>>(poses, posesbf);
  c_xinit<<<B_, 128, 0, stream>>>(poses, xcur, xbf);
  c_wcat<<<4096, 256, 0, stream>>>(gWih, gWhh, Wcat);
  c_bcat<<<16, 256, 0, stream>>>(gbih, gbhh, bcat);
  c_bf<<<4096, 256, 0, stream>>>(preW, prebf, 1024*1024);
  c_bf<<<4096, 256, 0, stream>>>(outW, outbf, 1024*1024);
  c_bf<<<12288, 256, 0, stream>>>(inW, inbf, 3072*1024);
  c_fpwt<<<128, 256, 0, stream>>>(fpW, fpwt);
  c_w1hid<<<7168, 256, 0, stream>>>(sW1, w1h);
  k_bc<<<48, 64, 0, stream>>>(inW, inb, fpb, bc);

  // W_c = inproj @ fp_W  (3072 x 128)
  gemm64<<<dim3(48, 2), 256, 0, stream>>>(inbf, fpwt, 1024, nullptr, nullptr, Wc, nullptr, 128, 0);
  k_qk<<<dim3(HEADS_, B_), 256, 0, stream>>>(Wc, bc, freq, att);
  k_soft<<<dim3(HEADS_, B_), 64, 0, stream>>>(att, colsum);
  k_vctx<<<dim3(HEADS_, B_), 256, 0, stream>>>(Wc, bc, freq, colsum, ctxbf);
  // motion_ctx = ctx_mean @ outproj^T + outb
  gemm64<<<dim3(4, 16), 256, 0, stream>>>(ctxbf, outbf, 1024, outb, nullptr, motion, nullptr, 1024, 0);

  float* hc = hA;  float* hn = hB;
  bf16*  hbc = hbA; bf16* hbn = hbB;

  // encoder: 120 fused GRU steps (h ping-pong)
  for (int t = 0; t < SEED_; ++t){
    gru_step<<<dim3(4, 16), 256, 0, stream>>>(posesbf + (size_t)t*256*128, hbc, hc, Wcat, bcat, hn, hbn);
    { float* tf = hc; hc = hn; hn = tf; bf16* tb = hbc; hbc = hbn; hbn = tb; }
  }
  // decoder: 24 steps
  for (int t = 0; t < PRED_; ++t){
    gru_step<<<dim3(4, 16), 256, 0, stream>>>(xbf, hbc, hc, Wcat, bcat, hn, hbn);
    { float* tf = hc; hc = hn; hn = tf; bf16* tb = hbc; hbc = hbn; hbn = tb; }
    // hid = relu(h @ pre^T + preb) + motion
    gemm64<<<dim3(4, 16), 256, 0, stream>>>(hbc, prebf, 1024, preb, motion, hid, hidbf, 1024, 1);
    // hh_pre = hid @ W1_hid^T + b1  (all 14 joints)
    gemm64<<<dim3(4, 28), 256, 0, stream>>>(hidbf, w1h, 1024, sb1, nullptr, hhpre, nullptr, 1792, 0);
    spl_all<<<64, 128, 0, stream>>>(hhpre, sW1, sW2, sb2, xcur, xbf, out, t);
  }
}

// Round 3
// 5383.474 us; speedup vs baseline: 1.1279x; 1.1250x over previous
//
#include <hip/hip_runtime.h>
#include <hip/hip_bf16.h>

typedef __hip_bfloat16 bf16;
typedef __attribute__((ext_vector_type(8))) short v8bf;     // 8 bf16 (4 VGPR)
typedef __attribute__((ext_vector_type(16))) float f32x16;

#define B_    256
#define SEED_ 120
#define PRED_ 24
#define D_    126
#define H_    1024
#define F_    61
#define HEADS_ 4
#define DH_   256

#define GLD16(lds, g) __builtin_amdgcn_global_load_lds( \
    (const __attribute__((address_space(1))) unsigned int*)(g), \
    (__attribute__((address_space(3))) unsigned int*)(lds), 16, 0, 0)
#define VMWAIT(n) asm volatile("s_waitcnt vmcnt(" #n ")" ::: "memory")
#define BARRIER() do { __builtin_amdgcn_s_barrier(); __builtin_amdgcn_sched_barrier(0); } while(0)

__device__ inline float b2f(unsigned short u){ return __uint_as_float(((unsigned)u) << 16); }

// ---------------- small precompute kernels ----------------
__global__ void k_cos(float* cosT){
  int i = blockIdx.x*256 + threadIdx.x;
  if (i < F_*SEED_){
    int f = i / SEED_, t = i % SEED_;
    int ph = (f*t) % SEED_;
    cosT[i] = cosf(6.283185307179586f * (float)ph / (float)SEED_);
  }
}

// freqbf[(b*61+f)*128 + d] (bf16, cols 126/127 zero)
__global__ void k_dft(const float* __restrict__ poses, const float* __restrict__ cosT,
                      bf16* __restrict__ freqbf){
  int f = blockIdx.x, b = blockIdx.y, d = threadIdx.x;  // block 128
  float acc = 0.f;
  if (d < D_){
    const float* pb = poses + (size_t)b*(SEED_+PRED_)*D_ + d;
    const float* ct = cosT + f*SEED_;
    for (int t = 0; t < SEED_; ++t) acc += ct[t] * pb[(size_t)t*D_];
  }
  freqbf[((size_t)b*F_ + f)*128 + d] = __float2bfloat16(d < D_ ? acc : 0.f);
}

__global__ void c_poses(const float* __restrict__ poses, bf16* __restrict__ pb){
  int t = blockIdx.x, b = blockIdx.y, c = threadIdx.x;  // block 128
  float v = (c < D_) ? poses[((size_t)b*(SEED_+PRED_) + t)*D_ + c] : 0.f;
  pb[((size_t)t*B_ + b)*128 + c] = __float2bfloat16(v);
}

__global__ void c_xinit(const float* __restrict__ poses, float* __restrict__ x, bf16* __restrict__ xbf){
  int b = blockIdx.x, c = threadIdx.x;  // block 128
  float v = (c < D_) ? poses[((size_t)b*(SEED_+PRED_) + (SEED_-1))*D_ + c] : 0.f;
  if (c < D_) x[b*D_ + c] = v;
  xbf[b*128 + c] = __float2bfloat16(v);
}

__global__ void c_bf(const float* __restrict__ s, bf16* __restrict__ d, int n){
  int i = blockIdx.x*256 + threadIdx.x;
  if (i < n) d[i] = __float2bfloat16(s[i]);
}

__global__ void c_fpwt(const float* __restrict__ fpW, bf16* __restrict__ o){
  int dd = blockIdx.x;                       // 0..127
  for (int k = threadIdx.x; k < H_; k += 256)
    o[(size_t)dd*H_ + k] = __float2bfloat16(dd < D_ ? fpW[(size_t)k*D_ + dd] : 0.f);
}

__global__ void c_w1hid(const float* __restrict__ W1, bf16* __restrict__ o){
  int i = blockIdx.x*256 + threadIdx.x;      // 1792*1024
  if (i < 1792*1024){ int r = i >> 10, c = i & 1023; o[i] = __float2bfloat16(W1[(size_t)r*1033 + c]); }
}

// combined GRU weight: rows 0..1023=[Wih_r|Whh_r]; 1024..2047=[Wih_z|Whh_z];
// 2048..3071=[Wih_n|0]; 3072..4095=[0|Whh_n]  (row width 1152 = 128 x | 1024 h)
__global__ void c_wcat(const float* __restrict__ Wih, const float* __restrict__ Whh, bf16* __restrict__ o){
  int r = blockIdx.x;
  int jr; bool hasx, hash;
  if (r < 2048){ jr = r; hasx = true; hash = true; }
  else if (r < 3072){ jr = r; hasx = true; hash = false; }
  else { jr = r - 1024; hasx = false; hash = true; }
  bf16* row = o + (size_t)r*1152;
  for (int c = threadIdx.x; c < 1152; c += 256){
    float v = 0.f;
    if (c < D_) { if (hasx) v = Wih[(size_t)jr*D_ + c]; }
    else if (c >= 128){ if (hash) v = Whh[(size_t)jr*H_ + (c-128)]; }
    row[c] = __float2bfloat16(v);
  }
}

__global__ void c_bcat(const float* __restrict__ bih, const float* __restrict__ bhh, float* __restrict__ o){
  int r = blockIdx.x*256 + threadIdx.x;
  if (r >= 4096) return;
  float v;
  if (r < 2048) v = bih[r] + bhh[r];
  else if (r < 3072) v = bih[r];
  else v = bhh[r - 1024];
  o[r] = v;
}

// bc = inproj @ fp_b + in_b : wave-per-row float4 reduction. grid 768, block 256.
__global__ __launch_bounds__(256) void k_bc(const float* __restrict__ inW, const float* __restrict__ inb,
                     const float* __restrict__ fpb, float* __restrict__ bc){
  int wave = threadIdx.x >> 6, lane = threadIdx.x & 63;
  int r = blockIdx.x*4 + wave;
  const float4* row = (const float4*)(inW + (size_t)r*H_);
  const float4* fp4 = (const float4*)fpb;
  float s = 0.f;
  #pragma unroll
  for (int i = 0; i < 4; ++i){
    float4 a = row[lane + i*64];
    float4 b = fp4[lane + i*64];
    s += a.x*b.x + a.y*b.y + a.z*b.z + a.w*b.w;
  }
  #pragma unroll
  for (int off = 32; off; off >>= 1) s += __shfl_down(s, off);
  if (lane == 0) bc[r] = s + inb[r];
}

// ---------------- fused GRU step (3-deep pipelined, counted vmcnt) ----------------
// grid (4 mb, 16 ub), block 256 (4 waves). Block: 64 batch x 64 units, 4 gate accumulators.
__global__ __launch_bounds__(256) void gru_step(
    const bf16* __restrict__ xsrc, const bf16* __restrict__ hbf_in,
    const float* __restrict__ h_in, const bf16* __restrict__ Wcat,
    const float* __restrict__ bcat, float* __restrict__ h_out, bf16* __restrict__ hbf_out)
{
  __shared__ bf16 As[3][64*64];        // 24 KB
  __shared__ bf16 Bs[3][3*64*64];      // 72 KB
  const int tid = threadIdx.x;
  const int wave = tid >> 6, lane = tid & 63;
  const int m0 = blockIdx.x*64, u0 = blockIdx.y*64;
  const int fr = lane & 31, kh = lane >> 5;
  const int wm = (wave >> 1)*32, wn = (wave & 1)*32;

  f32x16 accR = {0.f,0.f,0.f,0.f,0.f,0.f,0.f,0.f,0.f,0.f,0.f,0.f,0.f,0.f,0.f,0.f};
  f32x16 accZ = accR, accI = accR, accN = accR;

  auto STAGE = [&](int buf, int kt){
    #pragma unroll
    for (int q = 0; q < 2; ++q){           // A tile 64x64, inverse-swizzled source
      int idx = q*256 + tid;
      int row = idx >> 3, cp = idx & 7;
      int csw = cp ^ (row & 7);
      const bf16* src = (kt < 2) ? (xsrc   + (size_t)(m0+row)*128  + kt*64      + csw*8)
                                 : (hbf_in + (size_t)(m0+row)*1024 + (kt-2)*64  + csw*8);
      GLD16(&As[buf][idx*8], src);
    }
    #pragma unroll
    for (int q = 0; q < 6; ++q){           // B: 3 gate panels of 64x64
      int idx = q*256 + tid;
      int slot = idx >> 9, wi = idx & 511;
      int row = wi >> 3, cp = wi & 7;
      int csw = cp ^ (row & 7);
      int gate = (slot < 2) ? slot : (kt < 2 ? 2 : 3);
      const bf16* src = Wcat + (size_t)(gate*1024 + u0 + row)*1152 + kt*64 + csw*8;
      GLD16(&Bs[buf][idx*8], src);
    }
  };
  auto COMPUTE = [&](int buf, bool xp){
    const bf16* Ab = &As[buf][0];
    const bf16* Bb = &Bs[buf][0];
    #pragma unroll
    for (int ks = 0; ks < 4; ++ks){
      int ca = ks*2 + kh;
      v8bf av = *(const v8bf*)&Ab[(wm+fr)*64 + ((ca ^ ((wm+fr)&7))*8)];
      int bo = (wn+fr)*64 + ((ca ^ ((wn+fr)&7))*8);
      v8bf br = *(const v8bf*)&Bb[bo];
      v8bf bz = *(const v8bf*)&Bb[4096 + bo];
      v8bf bx = *(const v8bf*)&Bb[8192 + bo];
      accR = __builtin_amdgcn_mfma_f32_32x32x16_bf16(av, br, accR, 0, 0, 0);
      accZ = __builtin_amdgcn_mfma_f32_32x32x16_bf16(av, bz, accZ, 0, 0, 0);
      if (xp) accI = __builtin_amdgcn_mfma_f32_32x32x16_bf16(av, bx, accI, 0, 0, 0);
      else    accN = __builtin_amdgcn_mfma_f32_32x32x16_bf16(av, bx, accN, 0, 0, 0);
    }
  };

  STAGE(0, 0); STAGE(1, 1);
  VMWAIT(8); BARRIER();
  for (int kt = 0; kt < 18; ++kt){
    if (kt + 2 < 18) STAGE((kt+2)%3, kt+2);
    COMPUTE(kt%3, kt < 2);
    if (kt + 2 < 18){ VMWAIT(8); BARRIER(); }
    else if (kt + 1 < 18){ VMWAIT(0); BARRIER(); }
  }

  const int col = u0 + wn + fr;
  const float bR = bcat[col], bZ = bcat[1024+col], bI = bcat[2048+col], bN = bcat[3072+col];
  #pragma unroll
  for (int r = 0; r < 16; ++r){
    int row = m0 + wm + (r&3) + 8*(r>>2) + 4*kh;
    float rg = 1.f/(1.f + __expf(-(accR[r] + bR)));
    float zg = 1.f/(1.f + __expf(-(accZ[r] + bZ)));
    float ng = tanhf((accI[r] + bI) + rg*(accN[r] + bN));
    float ho = h_in[(size_t)row*1024 + col];
    float hv = (1.f - zg)*ng + zg*ho;
    h_out[(size_t)row*1024 + col] = hv;
    hbf_out[(size_t)row*1024 + col] = __float2bfloat16(hv);
  }
}

// ---------------- pipelined generic GEMM: C[M,N] = A @ B^T (+bias/epilogue) ----------------
// A: MxK, B: NxK bf16 row-major, K%64==0. grid (M/64, N/64), block 256. 3-buf counted-vmcnt.
__global__ __launch_bounds__(256) void gemm64(
    const bf16* __restrict__ Am, const bf16* __restrict__ Bm, int K,
    const float* __restrict__ bias, const float* __restrict__ addmat,
    float* __restrict__ C, bf16* __restrict__ Cbf, int N, int MODE)
{
  __shared__ bf16 As[3][64*64];
  __shared__ bf16 Bs[3][64*64];
  const int tid = threadIdx.x;
  const int wave = tid >> 6, lane = tid & 63;
  const int m0 = blockIdx.x*64, n0 = blockIdx.y*64;
  const int fr = lane & 31, kh = lane >> 5;
  const int wm = (wave >> 1)*32, wn = (wave & 1)*32;
  const int KT = K >> 6;

  f32x16 acc = {0.f,0.f,0.f,0.f,0.f,0.f,0.f,0.f,0.f,0.f,0.f,0.f,0.f,0.f,0.f,0.f};

  auto STAGE = [&](int buf, int kt){
    #pragma unroll
    for (int q = 0; q < 2; ++q){
      int idx = q*256 + tid;
      int row = idx >> 3, cp = idx & 7, csw = cp ^ (row & 7);
      GLD16(&As[buf][idx*8], Am + (size_t)(m0+row)*K + kt*64 + csw*8);
    }
    #pragma unroll
    for (int q = 0; q < 2; ++q){
      int idx = q*256 + tid;
      int row = idx >> 3, cp = idx & 7, csw = cp ^ (row & 7);
      GLD16(&Bs[buf][idx*8], Bm + (size_t)(n0+row)*K + kt*64 + csw*8);
    }
  };
  auto COMPUTE = [&](int buf){
    const bf16* Ab = &As[buf][0];
    const bf16* Bb = &Bs[buf][0];
    #pragma unroll
    for (int ks = 0; ks < 4; ++ks){
      int ca = ks*2 + kh;
      v8bf av = *(const v8bf*)&Ab[(wm+fr)*64 + ((ca ^ ((wm+fr)&7))*8)];
      v8bf bv = *(const v8bf*)&Bb[(wn+fr)*64 + ((ca ^ ((wn+fr)&7))*8)];
      acc = __builtin_amdgcn_mfma_f32_32x32x16_bf16(av, bv, acc, 0, 0, 0);
    }
  };

  STAGE(0, 0);
  if (KT > 1){ STAGE(1, 1); VMWAIT(4); } else { VMWAIT(0); }
  BARRIER();
  for (int kt = 0; kt < KT; ++kt){
    if (kt + 2 < KT) STAGE((kt+2)%3, kt+2);
    COMPUTE(kt%3);
    if (kt + 2 < KT){ VMWAIT(4); BARRIER(); }
    else if (kt + 1 < KT){ VMWAIT(0); BARRIER(); }
  }

  const int col = n0 + wn + fr;
  float bb = bias ? bias[col] : 0.f;
  #pragma unroll
  for (int r = 0; r < 16; ++r){
    int row = m0 + wm + (r&3) + 8*(r>>2) + 4*kh;
    float v = acc[r] + bb;
    if (MODE == 1) v = fmaxf(v, 0.f) + addmat[(size_t)row*N + col];
    if (C)   C[(size_t)row*N + col] = v;
    if (Cbf) Cbf[(size_t)row*N + col] = __float2bfloat16(v);
  }
}

// ---------------- attention: one block per (b,h) ----------------
// scores 64x64 = q(64x256)@k(64x256)^T via MFMA; softmax rows<61; colsum; ctx from global V.
__global__ __launch_bounds__(256) void k_attn(const bf16* __restrict__ qkv,
                                              bf16* __restrict__ ctxbf){
  __shared__ char smem[65536];
  bf16* qs = (bf16*)smem;               // [64][256] (32 chunks of 8, swizzled)
  bf16* ks = qs + 64*256;
  float* sc = (float*)smem;             // [64][65], reused over qs after barrier
  float* cs = (float*)(smem + 32768);   // reused over ks
  const int h = blockIdx.x, b = blockIdx.y;
  const int tid = threadIdx.x, wave = tid >> 6, lane = tid & 63;
  const int fr = lane & 31, kh = lane >> 5;
  const int wm = (wave >> 1)*32, wn = (wave & 1)*32;

  #pragma unroll
  for (int i = 0; i < 8; ++i){
    int idx = i*256 + tid;              // 0..2047
    int row = idx >> 5, cp = idx & 31, csw = cp ^ (row & 7);
    GLD16(&qs[idx*8], qkv + (size_t)(b*F_ + row)*3072 + h*DH_ + csw*8);
  }
  #pragma unroll
  for (int i = 0; i < 8; ++i){
    int idx = i*256 + tid;
    int row = idx >> 5, cp = idx & 31, csw = cp ^ (row & 7);
    GLD16(&ks[idx*8], qkv + (size_t)(b*F_ + row)*3072 + H_ + h*DH_ + csw*8);
  }
  __syncthreads();

  f32x16 acc = {0.f,0.f,0.f,0.f,0.f,0.f,0.f,0.f,0.f,0.f,0.f,0.f,0.f,0.f,0.f,0.f};
  #pragma unroll
  for (int i = 0; i < 16; ++i){
    int ca = i*2 + kh;
    v8bf av = *(const v8bf*)&qs[((wm+fr)*32 + (ca ^ ((wm+fr)&7)))*8];
    v8bf bv = *(const v8bf*)&ks[((wn+fr)*32 + (ca ^ ((wn+fr)&7)))*8];
    acc = __builtin_amdgcn_mfma_f32_32x32x16_bf16(av, bv, acc, 0, 0, 0);
  }
  __syncthreads();
  #pragma unroll
  for (int r = 0; r < 16; ++r){
    int row = wm + (r&3) + 8*(r>>2) + 4*kh;
    sc[row*65 + (wn+fr)] = acc[r]*0.0625f;
  }
  __syncthreads();
  if (tid < F_){
    float m = -1e30f;
    for (int k2 = 0; k2 < F_; ++k2) m = fmaxf(m, sc[tid*65+k2]);
    float s = 0.f;
    for (int k2 = 0; k2 < F_; ++k2){ float e = __expf(sc[tid*65+k2]-m); sc[tid*65+k2] = e; s += e; }
    float is = 1.f/s;
    for (int k2 = 0; k2 < F_; ++k2) sc[tid*65+k2] *= is;
  }
  __syncthreads();
  if (tid < F_){
    float s = 0.f;
    for (int r = 0; r < F_; ++r) s += sc[r*65+tid];
    cs[tid] = s;
  }
  __syncthreads();
  float a = 0.f;
  for (int k2 = 0; k2 < F_; ++k2){
    float v = __bfloat162float(qkv[(size_t)(b*F_+k2)*3072 + 2*H_ + h*DH_ + tid]);
    a += cs[k2]*v;
  }
  ctxbf[(size_t)b*H_ + h*DH_ + tid] = __float2bfloat16(a * (1.f/61.f));
}

// ---------------- SPL: parent chains + W2 head + x update ----------------
__constant__ int LVJ[14] = {0,1,6,8,9, 2,3,7,10,11, 4,5,12,13};
__constant__ int LVO[4]  = {0,5,10,14};
__constant__ int PAR_[14] = {-1,-1,0,1,2,3,-1,6,-1,-1,8,9,10,11};

__global__ __launch_bounds__(128) void spl_all(const float* __restrict__ hh_pre, const float* __restrict__ W1,
                        const float* __restrict__ W2, const float* __restrict__ b2,
                        float* __restrict__ x, bf16* __restrict__ xbf,
                        float* __restrict__ out, int tstep){
  __shared__ float preds_s[4][128];
  __shared__ float hh_s[128][5];
  int b0 = blockIdx.x*4, t = threadIdx.x;   // grid 64, block 128
  for (int L = 0; L < 3; ++L){
    for (int ji = LVO[L]; ji < LVO[L+1]; ++ji){
      int j = LVJ[ji], p = PAR_[j];
      float acc[4];
      #pragma unroll
      for (int bb = 0; bb < 4; ++bb) acc[bb] = hh_pre[(size_t)(b0+bb)*1792 + j*128 + t];
      if (p >= 0){
        #pragma unroll
        for (int ii = 0; ii < 9; ++ii){
          float w = W1[(size_t)(j*128 + t)*1033 + 1024 + ii];
          #pragma unroll
          for (int bb = 0; bb < 4; ++bb) acc[bb] += w * preds_s[bb][p*9 + ii];
        }
      }
      #pragma unroll
      for (int bb = 0; bb < 4; ++bb) hh_s[t][bb] = fmaxf(acc[bb], 0.f);
      __syncthreads();
      if (t < 72){
        int pp = t >> 1, half = t & 1;
        int bb = pp/9, oi = pp%9;
        const float* w2r = W2 + (size_t)(j*9 + oi)*128 + half*64;
        float s = 0.f;
        #pragma unroll
        for (int tt = 0; tt < 64; ++tt) s += hh_s[half*64 + tt][bb] * w2r[tt];
        s += __shfl_xor(s, 1);
        if (half == 0) preds_s[bb][j*9 + oi] = tanhf(s + b2[j*9 + oi]);
      }
      __syncthreads();
    }
  }
  for (int i = t; i < 4*D_; i += 128){
    int bb = i / D_, d = i % D_;
    size_t xi = (size_t)(b0+bb)*D_ + d;
    float v = x[xi] + preds_s[bb][d];
    x[xi] = v;
    xbf[(size_t)(b0+bb)*128 + d] = __float2bfloat16(v);
    out[((size_t)(b0+bb)*PRED_ + tstep)*D_ + d] = v;
  }
}

// ---------------- launch ----------------
extern "C" void kernel_launch(void* const* d_in, const int* in_sizes, int n_in,
                              void* d_out, int out_size, void* d_ws, size_t ws_size,
                              hipStream_t stream){
  (void)in_sizes; (void)n_in; (void)out_size; (void)ws_size;
  const float* poses = (const float*)d_in[0];
  const float* gWih  = (const float*)d_in[1];
  const float* gWhh  = (const float*)d_in[2];
  const float* gbih  = (const float*)d_in[3];
  const float* gbhh  = (const float*)d_in[4];
  const float* preW  = (const float*)d_in[5];
  const float* preb  = (const float*)d_in[6];
  const float* fpW   = (const float*)d_in[7];
  const float* fpb   = (const float*)d_in[8];
  const float* inW   = (const float*)d_in[9];
  const float* inb   = (const float*)d_in[10];
  const float* outW  = (const float*)d_in[11];
  const float* outb  = (const float*)d_in[12];
  const float* sW1   = (const float*)d_in[13];
  const float* sb1   = (const float*)d_in[14];
  const float* sW2   = (const float*)d_in[15];
  const float* sb2   = (const float*)d_in[16];
  float* out = (float*)d_out;

  char* w = (char*)d_ws;
  size_t off = 0;
  auto alloc = [&](size_t bytes)->char*{ char* p = w + off; off += (bytes + 255) & ~(size_t)255; return p; };
  float* cosT   = (float*)alloc(7320*4);
  float* bc     = (float*)alloc(3072*4);
  float* motion = (float*)alloc((size_t)256*1024*4);
  float* hA     = (float*)alloc((size_t)256*1024*4);
  float* hB     = (float*)alloc((size_t)256*1024*4);
  float* xcur   = (float*)alloc((size_t)256*126*4);
  float* hhpre  = (float*)alloc((size_t)256*1792*4);
  float* bcat   = (float*)alloc(4096*4);
  bf16* posesbf = (bf16*)alloc((size_t)120*256*128*2);
  bf16* Wcat    = (bf16*)alloc((size_t)4096*1152*2);
  bf16* prebf   = (bf16*)alloc((size_t)1024*1024*2);
  bf16* outbf   = (bf16*)alloc((size_t)1024*1024*2);
  bf16* inbf    = (bf16*)alloc((size_t)3072*1024*2);
  bf16* fpwt    = (bf16*)alloc((size_t)128*1024*2);
  bf16* w1h     = (bf16*)alloc((size_t)1792*1024*2);
  bf16* ctxbf   = (bf16*)alloc((size_t)256*1024*2);
  bf16* hbA     = (bf16*)alloc((size_t)256*1024*2);
  bf16* hbB     = (bf16*)alloc((size_t)256*1024*2);
  bf16* xbf     = (bf16*)alloc((size_t)256*128*2);
  bf16* hidbf   = (bf16*)alloc((size_t)256*1024*2);
  bf16* Wcbf    = (bf16*)alloc((size_t)3072*128*2);
  bf16* freqbf  = (bf16*)alloc((size_t)B_*F_*128*2);
  bf16* qkvbf   = (bf16*)alloc((size_t)15680*3072*2);   // 15616 rows + 64 pad

  hipMemsetAsync(hA, 0, (size_t)256*1024*4, stream);
  hipMemsetAsync(hbA, 0, (size_t)256*1024*2, stream);

  k_cos<<<29, 256, 0, stream>>>(cosT);
  k_dft<<<dim3(F_, B_), 128, 0, stream>>>(poses, cosT, freqbf);
  c_poses<<<dim3(SEED_, B_), 128, 0, stream>>>(poses, posesbf);
  c_xinit<<<B_, 128, 0, stream>>>(poses, xcur, xbf);
  c_wcat<<<4096, 256, 0, stream>>>(gWih, gWhh, Wcat);
  c_bcat<<<16, 256, 0, stream>>>(gbih, gbhh, bcat);
  c_bf<<<4096, 256, 0, stream>>>(preW, prebf, 1024*1024);
  c_bf<<<4096, 256, 0, stream>>>(outW, outbf, 1024*1024);
  c_bf<<<12288, 256, 0, stream>>>(inW, inbf, 3072*1024);
  c_fpwt<<<128, 256, 0, stream>>>(fpW, fpwt);
  c_w1hid<<<7168, 256, 0, stream>>>(sW1, w1h);
  k_bc<<<768, 256, 0, stream>>>(inW, inb, fpb, bc);

  // Wc = inproj @ fp_W  (3072 x 128, bf16)
  gemm64<<<dim3(48, 2), 256, 0, stream>>>(inbf, fpwt, 1024, nullptr, nullptr, nullptr, Wcbf, 128, 0);
  // qkv = freq @ Wc^T + bc  (15616 x 3072, bf16)
  gemm64<<<dim3(244, 48), 256, 0, stream>>>(freqbf, Wcbf, 128, bc, nullptr, nullptr, qkvbf, 3072, 0);
  k_attn<<<dim3(HEADS_, B_), 256, 0, stream>>>(qkvbf, ctxbf);
  // motion_ctx = ctx_mean @ outproj^T + outb
  gemm64<<<dim3(4, 16), 256, 0, stream>>>(ctxbf, outbf, 1024, outb, nullptr, motion, nullptr, 1024, 0);

  float* hc = hA;  float* hn = hB;
  bf16*  hbc = hbA; bf16* hbn = hbB;

  // encoder: 120 fused GRU steps (h ping-pong)
  for (int t = 0; t < SEED_; ++t){
    gru_step<<<dim3(4, 16), 256, 0, stream>>>(posesbf + (size_t)t*256*128, hbc, hc, Wcat, bcat, hn, hbn);
    { float* tf = hc; hc = hn; hn = tf; bf16* tb = hbc; hbc = hbn; hbn = tb; }
  }
  // decoder: 24 steps
  for (int t = 0; t < PRED_; ++t){
    gru_step<<<dim3(4, 16), 256, 0, stream>>>(xbf, hbc, hc, Wcat, bcat, hn, hbn);
    { float* tf = hc; hc = hn; hn = tf; bf16* tb = hbc; hbc = hbn; hbn = tb; }
    // hidbf = relu(h @ pre^T + preb) + motion
    gemm64<<<dim3(4, 16), 256, 0, stream>>>(hbc, prebf, 1024, preb, motion, nullptr, hidbf, 1024, 1);
    // hh_pre = hid @ W1_hid^T + b1  (all 14 joints)
    gemm64<<<dim3(4, 28), 256, 0, stream>>>(hidbf, w1h, 1024, sb1, nullptr, hhpre, nullptr, 1792, 0);
    spl_all<<<64, 128, 0, stream>>>(hhpre, sW1, sW2, sb2, xcur, xbf, out, t);
  }
}